// Round 2
// baseline (928.884 us; speedup 1.0000x reference)
//
#include <hip/hip_runtime.h>
#include <math.h>

#define N 320
#define NN (N * N)        // 102400
#define NV4 (N / 4)       // 80
#define KT 16
#define BSTR 324          // Bs/Ws row stride in floats (stagger banks for staging stores)
#define GSTR 36           // GsT row stride: 36*4=144B keeps float4 reads 16B-aligned

// ---------------- zero w buffer ----------------
__global__ __launch_bounds__(256) void zero_w_kernel(float* __restrict__ w) {
    int idx = blockIdx.x * 256 + threadIdx.x;
    ((float4*)w)[idx] = make_float4(0.f, 0.f, 0.f, 0.f);
}

// ---------------- colsum[e] = sum_t s[t][e] ----------------
__global__ __launch_bounds__(64) void colsum_kernel(const float* __restrict__ s,
                                                    float* __restrict__ colsum) {
    int e = blockIdx.x * 64 + threadIdx.x;
    float acc = 0.f;
    for (int t = 0; t < N; ++t) acc += s[t * N + e];
    colsum[e] = acc;
}

// ---------------- fused: per (e-slab of 32, i):
//   phase A: G[e][k] = sum_t s[t][e] * F_i[t][k]        -> GsT[k][e] in LDS
//   phase B: S[e][j] = sum_k G[e][k] * W[j][k] + cs[e]*b[j]  (registers)
//   softmax over j per e-row (width-32 shuffle), w[i][j] += sum_e p[e][j]
// Thread layout: ty = tid>>5 (8 groups x 4 e-rows), tx = tid&31 (32 groups x 10 cols).
// LDS: GsT 46KB + Bs 20.7KB + As 2KB + wacc 1.3KB = ~70KB -> 2 blocks/CU.
__global__ __launch_bounds__(256, 2) void fused_kernel(
    const float* __restrict__ s, const float* __restrict__ fut,
    const float* __restrict__ W, const float* __restrict__ bvec,
    const float* __restrict__ colsum, float* __restrict__ w)
{
    const int i  = blockIdx.y;
    const int e0 = blockIdx.x * 32;
    const int tid = threadIdx.x;
    const int ty  = tid >> 5;
    const int tx  = tid & 31;
    const int txj = tx * 10;
    const int ty4 = ty * 4;

    __shared__ float GsT[N * GSTR];     // [k][e] transposed G slab
    __shared__ float As[KT * 32];       // [t][e] s staging
    __shared__ float Bs[KT * BSTR];     // [t][j] F staging; reused as W^T staging
    __shared__ float wacc[N];

    for (int j = tid; j < N; j += 256) wacc[j] = 0.f;

    const float4* s4 = (const float4*)s;
    const float4* f4 = (const float4*)(fut + (size_t)i * NN);
    const float4* W4 = (const float4*)W;

    float acc[4][10];

    // ---------------- phase A ----------------
#pragma unroll
    for (int p = 0; p < 4; ++p)
#pragma unroll
        for (int q = 0; q < 10; ++q) acc[p][q] = 0.f;

    for (int t0 = 0; t0 < N; t0 += KT) {
        __syncthreads();
        if (tid < 128) {
            int r = tid >> 3, c4 = tid & 7;
            *(float4*)&As[r * 32 + c4 * 4] = s4[(t0 + r) * NV4 + (e0 >> 2) + c4];
        }
#pragma unroll
        for (int v = 0; v < 5; ++v) {
            int f = tid + 256 * v;
            int r = f / 80, c4 = f % 80;
            *(float4*)&Bs[r * BSTR + c4 * 4] = f4[(t0 + r) * NV4 + c4];
        }
        __syncthreads();
#pragma unroll
        for (int t = 0; t < KT; ++t) {
            float a[4], b[10];
            *(float4*)&a[0] = *(const float4*)&As[t * 32 + ty4];
            *(float2*)&b[0] = *(const float2*)&Bs[t * BSTR + txj + 0];
            *(float2*)&b[2] = *(const float2*)&Bs[t * BSTR + txj + 2];
            *(float2*)&b[4] = *(const float2*)&Bs[t * BSTR + txj + 4];
            *(float2*)&b[6] = *(const float2*)&Bs[t * BSTR + txj + 6];
            *(float2*)&b[8] = *(const float2*)&Bs[t * BSTR + txj + 8];
#pragma unroll
            for (int p = 0; p < 4; ++p)
#pragma unroll
                for (int q = 0; q < 10; ++q) acc[p][q] += a[p] * b[q];
        }
    }

    // G^T -> LDS (visibility guaranteed by phase-B post-staging barrier)
#pragma unroll
    for (int p = 0; p < 4; ++p)
#pragma unroll
        for (int q = 0; q < 10; ++q)
            GsT[(txj + q) * GSTR + ty4 + p] = acc[p][q];

    // ---------------- phase B ----------------
#pragma unroll
    for (int p = 0; p < 4; ++p)
#pragma unroll
        for (int q = 0; q < 10; ++q) acc[p][q] = 0.f;

    for (int k0 = 0; k0 < N; k0 += KT) {
        __syncthreads();   // also protects GsT stores / last phase-A Bs reads
#pragma unroll
        for (int v = 0; v < 5; ++v) {
            int f = tid + 256 * v;
            int j = f >> 2, cc = f & 3;
            float4 wv = W4[j * NV4 + (k0 >> 2) + cc];
            Bs[(cc * 4 + 0) * BSTR + j] = wv.x;
            Bs[(cc * 4 + 1) * BSTR + j] = wv.y;
            Bs[(cc * 4 + 2) * BSTR + j] = wv.z;
            Bs[(cc * 4 + 3) * BSTR + j] = wv.w;
        }
        __syncthreads();
#pragma unroll
        for (int t = 0; t < KT; ++t) {
            float a[4], b[10];
            *(float4*)&a[0] = *(const float4*)&GsT[(k0 + t) * GSTR + ty4];
            *(float2*)&b[0] = *(const float2*)&Bs[t * BSTR + txj + 0];
            *(float2*)&b[2] = *(const float2*)&Bs[t * BSTR + txj + 2];
            *(float2*)&b[4] = *(const float2*)&Bs[t * BSTR + txj + 4];
            *(float2*)&b[6] = *(const float2*)&Bs[t * BSTR + txj + 6];
            *(float2*)&b[8] = *(const float2*)&Bs[t * BSTR + txj + 8];
#pragma unroll
            for (int p = 0; p < 4; ++p)
#pragma unroll
                for (int q = 0; q < 10; ++q) acc[p][q] += a[p] * b[q];
        }
    }

    // ---------------- bias + softmax + w accumulation ----------------
    float cs[4], bj[10];
#pragma unroll
    for (int p = 0; p < 4; ++p) cs[p] = colsum[e0 + ty4 + p];
#pragma unroll
    for (int q = 0; q < 10; ++q) bj[q] = bvec[txj + q];

    float wpart[10];
#pragma unroll
    for (int q = 0; q < 10; ++q) wpart[q] = 0.f;

#pragma unroll
    for (int p = 0; p < 4; ++p) {
        float v[10];
#pragma unroll
        for (int q = 0; q < 10; ++q) v[q] = acc[p][q] + cs[p] * bj[q];
        float m = v[0];
#pragma unroll
        for (int q = 1; q < 10; ++q) m = fmaxf(m, v[q]);
#pragma unroll
        for (int off = 16; off; off >>= 1) m = fmaxf(m, __shfl_xor(m, off, 64));
        float sum = 0.f;
#pragma unroll
        for (int q = 0; q < 10; ++q) { v[q] = __expf(v[q] - m); sum += v[q]; }
#pragma unroll
        for (int off = 16; off; off >>= 1) sum += __shfl_xor(sum, off, 64);
        float inv = 1.0f / sum;
#pragma unroll
        for (int q = 0; q < 10; ++q) wpart[q] += v[q] * inv;
    }

#pragma unroll
    for (int q = 0; q < 10; ++q) atomicAdd(&wacc[txj + q], wpart[q]);
    __syncthreads();
    for (int j = tid; j < N; j += 256) atomicAdd(&w[(size_t)i * N + j], wacc[j]);
}

// ---------------- out[i][k] = sum_j w[i][j] * s[j][k] ----------------
__global__ __launch_bounds__(64) void out_gemm_kernel(
    const float* __restrict__ w, const float* __restrict__ s,
    float* __restrict__ out)
{
    const int k = blockIdx.x * 64 + threadIdx.x;
    const int i = blockIdx.y;
    const float* wr = w + (size_t)i * N;
    float acc = 0.f;
    for (int j = 0; j < N; ++j) acc += wr[j] * s[j * N + k];
    out[(size_t)i * N + k] = acc;
}

extern "C" void kernel_launch(void* const* d_in, const int* in_sizes, int n_in,
                              void* d_out, int out_size, void* d_ws, size_t ws_size,
                              hipStream_t stream)
{
    const float* s    = (const float*)d_in[0];
    const float* fut  = (const float*)d_in[1];
    const float* W    = (const float*)d_in[2];
    const float* bvec = (const float*)d_in[3];
    float* out = (float*)d_out;

    float* wbuf   = (float*)d_ws;          // NN floats
    float* colsum = wbuf + NN;             // N floats

    zero_w_kernel<<<dim3(NN / 4 / 256), dim3(256), 0, stream>>>(wbuf);
    colsum_kernel<<<dim3(N / 64), dim3(64), 0, stream>>>(s, colsum);
    fused_kernel<<<dim3(10, N), dim3(256), 0, stream>>>(s, fut, W, bvec, colsum, wbuf);
    out_gemm_kernel<<<dim3(5, N), dim3(64), 0, stream>>>(wbuf, s, out);
}

// Round 3
// 451.619 us; speedup vs baseline: 2.0568x; 2.0568x over previous
//
#include <hip/hip_runtime.h>
#include <hip/hip_bf16.h>
#include <math.h>

#define N 320
#define NN (N * N)          // 102400
#define AST 328             // LDS bf16 row stride for G (656B, 16B-aligned)
#define SST 324             // LDS fp32 row stride for S scratch

typedef float f32x16 __attribute__((ext_vector_type(16)));
typedef short s16x8  __attribute__((ext_vector_type(8)));

#define MFMA32(a, b, c) __builtin_amdgcn_mfma_f32_32x32x16_bf16((a), (b), (c), 0, 0, 0)

union U4V { uint4 q; s16x8 v; };
union UAV { unsigned u[4]; s16x8 v; };
union BFU { __hip_bfloat16 b; unsigned short u; };

// split x into bf16 hi + bf16 lo (x ~= hi + lo)
__device__ inline void bsplit(float x, unsigned short& h, unsigned short& l) {
    __hip_bfloat16 hb = __float2bfloat16(x);
    float r = __bfloat162float(hb);
    __hip_bfloat16 lb = __float2bfloat16(x - r);
    BFU a; a.b = hb; h = a.u;
    BFU c; c.b = lb; l = c.u;
}
__device__ inline void split2(float x0, float x1, unsigned& hi, unsigned& lo) {
    unsigned short h0, l0, h1, l1;
    bsplit(x0, h0, l0); bsplit(x1, h1, l1);
    hi = (unsigned)h0 | ((unsigned)h1 << 16);
    lo = (unsigned)l0 | ((unsigned)l1 << 16);
}

// ---------------- zero w buffer ----------------
__global__ __launch_bounds__(256) void zero_w_kernel(float* __restrict__ w) {
    int idx = blockIdx.x * 256 + threadIdx.x;
    ((float4*)w)[idx] = make_float4(0.f, 0.f, 0.f, 0.f);
}

// ---------------- colsum[e] = sum_t s[t][e] ----------------
__global__ __launch_bounds__(64) void colsum_kernel(const float* __restrict__ s,
                                                    float* __restrict__ colsum) {
    int e = blockIdx.x * 64 + threadIdx.x;
    float acc = 0.f;
    for (int t = 0; t < N; ++t) acc += s[t * N + e];
    colsum[e] = acc;
}

// ---------------- pack s^T into A-fragments (bf16 hi/lo) ----------------
// frag-block blk = et*20 + ts; lane l holds A[m=e][k=t] with e = et*32+(l&31),
// t = ts*16 + (l>>5)*8 + j, j=0..7 (k-pairs per dword).
__global__ __launch_bounds__(64) void pack_s_kernel(const float* __restrict__ s,
                                                    uint4* __restrict__ spH,
                                                    uint4* __restrict__ spL) {
    int blk = blockIdx.x;          // 0..199
    int l = threadIdx.x;
    int et = blk / 20, ts = blk % 20;
    int e = et * 32 + (l & 31);
    int t0 = ts * 16 + (l >> 5) * 8;
    unsigned hi[4], lo[4];
#pragma unroll
    for (int d = 0; d < 4; ++d) {
        float x0 = s[(t0 + 2 * d) * N + e];
        float x1 = s[(t0 + 2 * d + 1) * N + e];
        split2(x0, x1, hi[d], lo[d]);
    }
    spH[blk * 64 + l] = make_uint4(hi[0], hi[1], hi[2], hi[3]);
    spL[blk * 64 + l] = make_uint4(lo[0], lo[1], lo[2], lo[3]);
}

// ---------------- pack W^T into B-fragments (bf16 hi/lo) ----------------
// frag-block blk = jt*20 + ks; lane l holds B[k][n=j] = W[j][k] with
// j = jt*32 + (l&31), k = ks*16 + (l>>5)*8 + jj.
__global__ __launch_bounds__(64) void pack_w_kernel(const float* __restrict__ W,
                                                    uint4* __restrict__ wpH,
                                                    uint4* __restrict__ wpL) {
    int blk = blockIdx.x;          // 0..199
    int l = threadIdx.x;
    int jt = blk / 20, ks = blk % 20;
    int j = jt * 32 + (l & 31);
    int k0 = ks * 16 + (l >> 5) * 8;
    const float* wr = W + (size_t)j * N + k0;
    unsigned hi[4], lo[4];
#pragma unroll
    for (int d = 0; d < 4; ++d) split2(wr[2 * d], wr[2 * d + 1], hi[d], lo[d]);
    wpH[blk * 64 + l] = make_uint4(hi[0], hi[1], hi[2], hi[3]);
    wpL[blk * 64 + l] = make_uint4(lo[0], lo[1], lo[2], lo[3]);
}

// ---------------- fused MFMA kernel: per (e-slab 32, i) ----------------
__global__ __launch_bounds__(640, 5) void fused_kernel(
    const float* __restrict__ fut,
    const uint4* __restrict__ spH, const uint4* __restrict__ spL,
    const uint4* __restrict__ wpH, const uint4* __restrict__ wpL,
    const float* __restrict__ bvec, const float* __restrict__ colsum,
    float* __restrict__ w)
{
    const int i   = blockIdx.y;
    const int et  = blockIdx.x;       // e0 = et*32
    const int tid = threadIdx.x;
    const int wid = tid >> 6;         // wave 0..9 = column tile
    const int lane = tid & 63;
    const int l31 = lane & 31;
    const int hf  = lane >> 5;

    __shared__ union {
        struct { unsigned short H[32 * AST]; unsigned short L[32 * AST]; } a;
        float S[32 * SST];
    } sm;
    __shared__ float csh[32];
    __shared__ float Mfin[32];
    __shared__ float Ifin[32];

    if (tid < 32) csh[tid] = colsum[et * 32 + tid];

    // ---------------- phase A: G = s^T @ F_i (column tile wid) ----------------
    f32x16 acc;
#pragma unroll
    for (int r = 0; r < 16; ++r) acc[r] = 0.f;

    const float* fbase = fut + (size_t)i * NN + (size_t)(hf * 8) * N + wid * 32 + l31;
    const uint4* aH = spH + (size_t)(et * 20) * 64 + lane;
    const uint4* aL = spL + (size_t)(et * 20) * 64 + lane;

    for (int ts = 0; ts < 20; ++ts) {
        const float* fp = fbase + (size_t)(ts * 16) * N;
        float f[8];
#pragma unroll
        for (int j = 0; j < 8; ++j) f[j] = fp[j * N];
        U4V ah; ah.q = aH[ts * 64];
        U4V al; al.q = aL[ts * 64];
        UAV bh, bl;
#pragma unroll
        for (int d = 0; d < 4; ++d) split2(f[2 * d], f[2 * d + 1], bh.u[d], bl.u[d]);
        acc = MFMA32(ah.v, bh.v, acc);
        acc = MFMA32(al.v, bh.v, acc);
        acc = MFMA32(ah.v, bl.v, acc);
    }

    // G -> LDS as bf16 hi/lo, A-fragment friendly layout [e][c]
#pragma unroll
    for (int r = 0; r < 16; ++r) {
        int e = (r & 3) + ((r >> 2) << 3) + (hf << 2);
        unsigned short h, l;
        bsplit(acc[r], h, l);
        sm.a.H[e * AST + wid * 32 + l31] = h;
        sm.a.L[e * AST + wid * 32 + l31] = l;
    }
    __syncthreads();   // B1: G visible (also csh)

    // ---------------- phase B: S = G @ W^T (+ bias) ----------------
    f32x16 acc2;
#pragma unroll
    for (int r = 0; r < 16; ++r) acc2[r] = 0.f;

    const uint4* bH = wpH + (size_t)(wid * 20) * 64 + lane;
    const uint4* bL = wpL + (size_t)(wid * 20) * 64 + lane;

    for (int ks = 0; ks < 20; ++ks) {
        int aoff = l31 * AST + ks * 16 + hf * 8;
        s16x8 gah = *(const s16x8*)&sm.a.H[aoff];
        s16x8 gal = *(const s16x8*)&sm.a.L[aoff];
        U4V wh; wh.q = bH[ks * 64];
        U4V wl; wl.q = bL[ks * 64];
        acc2 = MFMA32(gah, wh.v, acc2);
        acc2 = MFMA32(gal, wh.v, acc2);
        acc2 = MFMA32(gah, wl.v, acc2);
    }

    // bias: v[r] = acc2[r] + colsum[e]*b[j]
    const int jcol = wid * 32 + l31;
    float bj = bvec[jcol];
    float v[16];
#pragma unroll
    for (int r = 0; r < 16; ++r) {
        int e = (r & 3) + ((r >> 2) << 3) + (hf << 2);
        v[r] = acc2[r] + csh[e] * bj;
    }

    __syncthreads();   // B2: all waves done reading G before S overwrites the union

    // write S[e][j] to LDS for row-wise softmax stats
#pragma unroll
    for (int r = 0; r < 16; ++r) {
        int e = (r & 3) + ((r >> 2) << 3) + (hf << 2);
        sm.S[e * SST + jcol] = v[r];
    }
    __syncthreads();   // B3

    // row sweeps: half-wave hw (0..15) handles rows 2hw, 2hw+1
    const int hw = tid >> 5;          // global half-wave id 0..19
    const int li = tid & 31;
    if (hw < 16) {
#pragma unroll
        for (int rr = 0; rr < 2; ++rr) {
            int row = 2 * hw + rr;
            float x[10];
            float m = -3.4e38f;
#pragma unroll
            for (int q = 0; q < 10; ++q) {
                x[q] = sm.S[row * SST + li + 32 * q];
                m = fmaxf(m, x[q]);
            }
#pragma unroll
            for (int off = 16; off; off >>= 1) m = fmaxf(m, __shfl_xor(m, off, 64));
            float ssum = 0.f;
#pragma unroll
            for (int q = 0; q < 10; ++q) ssum += __expf(x[q] - m);
#pragma unroll
            for (int off = 16; off; off >>= 1) ssum += __shfl_xor(ssum, off, 64);
            if (li == 0) { Mfin[row] = m; Ifin[row] = 1.0f / ssum; }
        }
    }
    __syncthreads();   // B4

    // p = exp(v - m) * inv ; column-sum over e ; accumulate w[i][j]
    float wcol = 0.f;
#pragma unroll
    for (int r = 0; r < 16; ++r) {
        int e = (r & 3) + ((r >> 2) << 3) + (hf << 2);
        wcol += __expf(v[r] - Mfin[e]) * Ifin[e];
    }
    wcol += __shfl_xor(wcol, 32, 64);
    if (hf == 0) atomicAdd(&w[(size_t)i * N + jcol], wcol);
}

// ---------------- out[i][k] = sum_j w[i][j] * s[j][k] ----------------
__global__ __launch_bounds__(64) void out_gemm_kernel(
    const float* __restrict__ w, const float* __restrict__ s,
    float* __restrict__ out)
{
    const int k = blockIdx.x * 64 + threadIdx.x;
    const int i = blockIdx.y;
    const float* wr = w + (size_t)i * N;
    float acc = 0.f;
    for (int j = 0; j < N; ++j) acc += wr[j] * s[j * N + k];
    out[(size_t)i * N + k] = acc;
}

extern "C" void kernel_launch(void* const* d_in, const int* in_sizes, int n_in,
                              void* d_out, int out_size, void* d_ws, size_t ws_size,
                              hipStream_t stream)
{
    const float* s    = (const float*)d_in[0];
    const float* fut  = (const float*)d_in[1];
    const float* W    = (const float*)d_in[2];
    const float* bvec = (const float*)d_in[3];
    float* out = (float*)d_out;

    char* base = (char*)d_ws;
    float* wbuf   = (float*)base;                        // NN floats   (409600 B)
    float* colsum = (float*)(base + 409600);             // N floats    (1280 B)
    uint4* spH = (uint4*)(base + 410880);                // 204800 B
    uint4* spL = (uint4*)(base + 615680);                // 204800 B
    uint4* wpH = (uint4*)(base + 820480);                // 204800 B
    uint4* wpL = (uint4*)(base + 1025280);               // 204800 B

    zero_w_kernel<<<dim3(NN / 4 / 256), dim3(256), 0, stream>>>(wbuf);
    colsum_kernel<<<dim3(N / 64), dim3(64), 0, stream>>>(s, colsum);
    pack_s_kernel<<<dim3(200), dim3(64), 0, stream>>>(s, spH, spL);
    pack_w_kernel<<<dim3(200), dim3(64), 0, stream>>>(W, wpH, wpL);

    fused_kernel<<<dim3(10, N), dim3(640), 0, stream>>>(
        fut, spH, spL, wpH, wpL, bvec, colsum, wbuf);

    out_gemm_kernel<<<dim3(N / 64, N), dim3(64), 0, stream>>>(wbuf, s, out);
}

// Round 4
// 384.300 us; speedup vs baseline: 2.4171x; 1.1752x over previous
//
#include <hip/hip_runtime.h>
#include <hip/hip_bf16.h>
#include <math.h>

#define N 320
#define NN (N * N)          // 102400
#define SST 324             // LDS fp32 row stride for S scratch
#define ZCNT (NN + N)       // floats to zero (wbuf + colsum)

typedef float f32x16 __attribute__((ext_vector_type(16)));
typedef short s16x8  __attribute__((ext_vector_type(8)));

#define MFMA32(a, b, c) __builtin_amdgcn_mfma_f32_32x32x16_bf16((a), (b), (c), 0, 0, 0)

union U4V { uint4 q; s16x8 v; };
union UAV { unsigned u[4]; s16x8 v; };

// truncation split: x = hi + lo with hi,lo bf16 (round-toward-zero; rel err ~2^-16 combined)
__device__ inline void split2(float x0, float x1, unsigned& hi, unsigned& lo) {
    unsigned u0 = __float_as_uint(x0), u1 = __float_as_uint(x1);
    hi = (u0 >> 16) | (u1 & 0xFFFF0000u);
    float d0 = x0 - __uint_as_float(u0 & 0xFFFF0000u);
    float d1 = x1 - __uint_as_float(u1 & 0xFFFF0000u);
    lo = (__float_as_uint(d0) >> 16) | (__float_as_uint(d1) & 0xFFFF0000u);
}

// ---------------- zero wbuf + colsum ----------------
__global__ __launch_bounds__(256) void zero_w_kernel(float* __restrict__ w) {
    int idx = blockIdx.x * 256 + threadIdx.x;
    if (idx * 4 < ZCNT) ((float4*)w)[idx] = make_float4(0.f, 0.f, 0.f, 0.f);
}

// ---------------- colsum[e] += partial sums over 40-row chunks ----------------
__global__ __launch_bounds__(64) void colsum_kernel(const float* __restrict__ s,
                                                    float* __restrict__ colsum) {
    int e = blockIdx.x * 64 + threadIdx.x;
    int t0 = blockIdx.y * 40;
    float a[8];
#pragma unroll
    for (int u = 0; u < 8; ++u) a[u] = 0.f;
    for (int t = 0; t < 40; t += 8) {
#pragma unroll
        for (int u = 0; u < 8; ++u) a[u] += s[(size_t)(t0 + t + u) * N + e];
    }
    float sum = ((a[0] + a[1]) + (a[2] + a[3])) + ((a[4] + a[5]) + (a[6] + a[7]));
    atomicAdd(&colsum[e], sum);
}

// ---------------- pack s^T into A-fragments (bf16 hi/lo) ----------------
__global__ __launch_bounds__(64) void pack_s_kernel(const float* __restrict__ s,
                                                    uint4* __restrict__ spH,
                                                    uint4* __restrict__ spL) {
    int blk = blockIdx.x;          // 0..199 = et*20 + ts
    int l = threadIdx.x;
    int et = blk / 20, ts = blk % 20;
    int e = et * 32 + (l & 31);
    int t0 = ts * 16 + (l >> 5) * 8;
    unsigned hi[4], lo[4];
#pragma unroll
    for (int d = 0; d < 4; ++d)
        split2(s[(size_t)(t0 + 2 * d) * N + e], s[(size_t)(t0 + 2 * d + 1) * N + e],
               hi[d], lo[d]);
    spH[blk * 64 + l] = make_uint4(hi[0], hi[1], hi[2], hi[3]);
    spL[blk * 64 + l] = make_uint4(lo[0], lo[1], lo[2], lo[3]);
}

// ---------------- pack W^T into B-fragments (bf16 hi/lo) ----------------
__global__ __launch_bounds__(64) void pack_w_kernel(const float* __restrict__ W,
                                                    uint4* __restrict__ wpH,
                                                    uint4* __restrict__ wpL) {
    int blk = blockIdx.x;          // 0..199 = jt*20 + ks
    int l = threadIdx.x;
    int jt = blk / 20, ks = blk % 20;
    int j = jt * 32 + (l & 31);
    int k0 = ks * 16 + (l >> 5) * 8;
    const float* wr = W + (size_t)j * N + k0;
    unsigned hi[4], lo[4];
#pragma unroll
    for (int d = 0; d < 4; ++d) split2(wr[2 * d], wr[2 * d + 1], hi[d], lo[d]);
    wpH[blk * 64 + l] = make_uint4(hi[0], hi[1], hi[2], hi[3]);
    wpL[blk * 64 + l] = make_uint4(lo[0], lo[1], lo[2], lo[3]);
}

// ---------------- fused MFMA kernel: per (e-slab 32, i) ----------------
// Grid is 1-D (3200) with an XCD swizzle: all 10 e-slabs of one i map to the
// same XCD (bid%8 == i%8) so F_i is served from that XCD's L2 after first touch.
__global__ __launch_bounds__(640, 5) void fused_kernel(
    const float* __restrict__ fut,
    const uint4* __restrict__ spH, const uint4* __restrict__ spL,
    const uint4* __restrict__ wpH, const uint4* __restrict__ wpL,
    const float* __restrict__ bvec, const float* __restrict__ colsum,
    float* __restrict__ w)
{
    const int bid = blockIdx.x;
    const int i   = (bid / 80) * 8 + (bid & 7);
    const int et  = (bid >> 3) % 10;
    const int tid = threadIdx.x;
    const int wid = tid >> 6;         // wave 0..9 = 32-wide column tile
    const int lane = tid & 63;
    const int l31 = lane & 31;
    const int hf  = lane >> 5;

    // G in LDS: frag-linear, XOR-swizzled 16B chunks.
    // chunk c = ks*2+hf (0..39); addr = (c*32 + (e ^ (c&7)))*8 shorts + j
    __shared__ union {
        unsigned short G[2][40 * 32 * 8];   // [hi/lo] 20KB each
        float S[32 * SST];                  // softmax scratch
    } sm;
    __shared__ float csh[32];
    __shared__ float Mfin[32];
    __shared__ float Ifin[32];

    if (tid < 32) csh[tid] = colsum[et * 32 + tid];

    // ---------------- phase A: G = s^T @ F_i (column tile wid) ----------------
    f32x16 acc;
#pragma unroll
    for (int r = 0; r < 16; ++r) acc[r] = 0.f;

    const float* fbase = fut + (size_t)i * NN + (size_t)(hf * 8) * N + wid * 32 + l31;
    const uint4* aH = spH + (size_t)(et * 20) * 64 + lane;
    const uint4* aL = spL + (size_t)(et * 20) * 64 + lane;

    for (int ts = 0; ts < 20; ++ts) {
        const float* fp = fbase + (size_t)(ts * 16) * N;
        float f[8];
#pragma unroll
        for (int j = 0; j < 8; ++j) f[j] = fp[j * N];
        U4V ah; ah.q = aH[ts * 64];
        U4V al; al.q = aL[ts * 64];
        UAV bh, bl;
#pragma unroll
        for (int d = 0; d < 4; ++d) split2(f[2 * d], f[2 * d + 1], bh.u[d], bl.u[d]);
        acc = MFMA32(ah.v, bh.v, acc);
        acc = MFMA32(al.v, bh.v, acc);
        acc = MFMA32(ah.v, bl.v, acc);
    }

    // G -> LDS bf16 hi/lo in frag-linear swizzled layout
    {
        const int c  = wid * 4 + (l31 >> 3);
        const int jj = l31 & 7;
        const int sw = c & 7;
        unsigned short* GH = sm.G[0];
        unsigned short* GL = sm.G[1];
#pragma unroll
        for (int r = 0; r < 16; ++r) {
            int e = (r & 3) + ((r >> 2) << 3) + (hf << 2);
            float x = acc[r];
            unsigned u = __float_as_uint(x);
            float d = x - __uint_as_float(u & 0xFFFF0000u);
            int off = (c * 32 + (e ^ sw)) * 8 + jj;
            GH[off] = (unsigned short)(u >> 16);
            GL[off] = (unsigned short)(__float_as_uint(d) >> 16);
        }
    }
    __syncthreads();   // B1: G + csh visible

    // ---------------- phase B: S = G @ W^T (+ bias) ----------------
    f32x16 acc2;
#pragma unroll
    for (int r = 0; r < 16; ++r) acc2[r] = 0.f;

    const uint4* bH = wpH + (size_t)(wid * 20) * 64 + lane;
    const uint4* bL = wpL + (size_t)(wid * 20) * 64 + lane;
    const unsigned short* GH = sm.G[0];
    const unsigned short* GL = sm.G[1];

#pragma unroll 4
    for (int ks = 0; ks < 20; ++ks) {
        int c0 = ks * 2 + hf;
        int aoff = (c0 * 32 + (l31 ^ (c0 & 7))) * 8;
        s16x8 gah = *(const s16x8*)&GH[aoff];
        s16x8 gal = *(const s16x8*)&GL[aoff];
        U4V wh; wh.q = bH[ks * 64];
        U4V wl; wl.q = bL[ks * 64];
        acc2 = MFMA32(gah, wh.v, acc2);
        acc2 = MFMA32(gal, wh.v, acc2);
        acc2 = MFMA32(gah, wl.v, acc2);
    }

    const int jcol = wid * 32 + l31;
    float bj = bvec[jcol];
    float v[16];
#pragma unroll
    for (int r = 0; r < 16; ++r) {
        int e = (r & 3) + ((r >> 2) << 3) + (hf << 2);
        v[r] = acc2[r] + csh[e] * bj;
    }

    __syncthreads();   // B2: all waves done reading G before S overwrites union

#pragma unroll
    for (int r = 0; r < 16; ++r) {
        int e = (r & 3) + ((r >> 2) << 3) + (hf << 2);
        sm.S[e * SST + jcol] = v[r];
    }
    __syncthreads();   // B3

    // row sweeps: half-wave hw (0..15) handles rows 2hw, 2hw+1
    const int hw = tid >> 5;
    const int li = tid & 31;
    if (hw < 16) {
#pragma unroll
        for (int rr = 0; rr < 2; ++rr) {
            int row = 2 * hw + rr;
            float x[10];
            float m = -3.4e38f;
#pragma unroll
            for (int q = 0; q < 10; ++q) {
                x[q] = sm.S[row * SST + li + 32 * q];
                m = fmaxf(m, x[q]);
            }
#pragma unroll
            for (int off = 16; off; off >>= 1) m = fmaxf(m, __shfl_xor(m, off, 64));
            float ssum = 0.f;
#pragma unroll
            for (int q = 0; q < 10; ++q) ssum += __expf(x[q] - m);
#pragma unroll
            for (int off = 16; off; off >>= 1) ssum += __shfl_xor(ssum, off, 64);
            if (li == 0) { Mfin[row] = m; Ifin[row] = 1.0f / ssum; }
        }
    }
    __syncthreads();   // B4

    float wcol = 0.f;
#pragma unroll
    for (int r = 0; r < 16; ++r) {
        int e = (r & 3) + ((r >> 2) << 3) + (hf << 2);
        wcol += __expf(v[r] - Mfin[e]) * Ifin[e];
    }
    wcol += __shfl_xor(wcol, 32, 64);
    if (hf == 0) atomicAdd(&w[(size_t)i * N + jcol], wcol);
}

// ---------------- out[i][k] = sum_j w[i][j] * s[j][k] ----------------
__global__ __launch_bounds__(320) void out_gemm_kernel(
    const float* __restrict__ w, const float* __restrict__ s,
    float* __restrict__ out)
{
    const int i = blockIdx.x;
    const int k = threadIdx.x;
    const float* wr = w + (size_t)i * N;
    float a0 = 0.f, a1 = 0.f, a2 = 0.f, a3 = 0.f;
    for (int j = 0; j < N; j += 4) {
        a0 += wr[j + 0] * s[(size_t)(j + 0) * N + k];
        a1 += wr[j + 1] * s[(size_t)(j + 1) * N + k];
        a2 += wr[j + 2] * s[(size_t)(j + 2) * N + k];
        a3 += wr[j + 3] * s[(size_t)(j + 3) * N + k];
    }
    out[(size_t)i * N + k] = (a0 + a1) + (a2 + a3);
}

extern "C" void kernel_launch(void* const* d_in, const int* in_sizes, int n_in,
                              void* d_out, int out_size, void* d_ws, size_t ws_size,
                              hipStream_t stream)
{
    const float* s    = (const float*)d_in[0];
    const float* fut  = (const float*)d_in[1];
    const float* W    = (const float*)d_in[2];
    const float* bvec = (const float*)d_in[3];
    float* out = (float*)d_out;

    char* base = (char*)d_ws;
    float* wbuf   = (float*)base;                        // NN floats (409600 B)
    float* colsum = (float*)(base + 409600);             // N floats  (1280 B)
    uint4* spH = (uint4*)(base + 410880);                // 204800 B
    uint4* spL = (uint4*)(base + 615680);                // 204800 B
    uint4* wpH = (uint4*)(base + 820480);                // 204800 B
    uint4* wpL = (uint4*)(base + 1025280);               // 204800 B

    zero_w_kernel<<<dim3((ZCNT / 4 + 255) / 256), dim3(256), 0, stream>>>(wbuf);
    colsum_kernel<<<dim3(5, 8), dim3(64), 0, stream>>>(s, colsum);
    pack_s_kernel<<<dim3(200), dim3(64), 0, stream>>>(s, spH, spL);
    pack_w_kernel<<<dim3(200), dim3(64), 0, stream>>>(W, wpH, wpL);

    fused_kernel<<<dim3(3200), dim3(640), 0, stream>>>(
        fut, spH, spL, wpH, wpL, bvec, colsum, wbuf);

    out_gemm_kernel<<<dim3(N), dim3(320), 0, stream>>>(wbuf, s, out);
}